// Round 2
// baseline (12053.774 us; speedup 1.0000x reference)
//
#include <hip/hip_runtime.h>

typedef unsigned short u16;

__device__ __forceinline__ float b2f(u16 u) {
  unsigned int x = ((unsigned int)u) << 16;
  float f; __builtin_memcpy(&f, &x, 4); return f;
}
__device__ __forceinline__ u16 f2b(float f) {
  unsigned int x; __builtin_memcpy(&x, &f, 4);
  unsigned int r = x + 0x7fffu + ((x >> 16) & 1u);
  return (u16)(r >> 16);
}

// ---------------------------------------------------------------------------
// Generic GEMM: C[M,N] = act(A[M,K] @ B[K,N] + biasF). fp32 accumulate.
// AF/BF/CF: 1 = fp32 storage, 0 = bf16 storage. C2 (optional) always fp32.
// Optional A-row remap: phys = (r>>ms)*smap + n0 + (r & ((1<<ms)-1))
// ---------------------------------------------------------------------------
template<int AF, int BF, int CF>
__global__ __launch_bounds__(256) void gemm_t(
    const void* __restrict__ Ap, int lda,
    const void* __restrict__ Bp, int ldb,
    const float* __restrict__ biasF,
    void* __restrict__ Cp, int ldc, float* __restrict__ C2, int ldc2,
    int M, int N, int K, int act, int map_shift, int n0, int smap)
{
  __shared__ float As[16][132];   // [k][m], padded
  __shared__ float Bs[16][128];   // [k][n]
  const int tid = threadIdx.x;
  const int tx = tid & 15, ty = tid >> 4;
  const int row0 = blockIdx.y << 7, col0 = blockIdx.x << 7;

  float acc[8][8];
#pragma unroll
  for (int i = 0; i < 8; ++i)
#pragma unroll
    for (int j = 0; j < 8; ++j) acc[i][j] = 0.f;

  for (int kt = 0; kt < K; kt += 16) {
#pragma unroll
    for (int u = 0; u < 8; ++u) {            // A tile: 128 x 16
      int i = tid + (u << 8);
      int m = i >> 4, k = i & 15;
      int gr = row0 + m;
      float v = 0.f;
      if (gr < M) {
        int pr = gr;
        if (map_shift >= 0)
          pr = ((gr >> map_shift) * smap) + n0 + (gr & ((1 << map_shift) - 1));
        size_t idx = (size_t)pr * lda + kt + k;
        v = AF ? ((const float*)Ap)[idx] : b2f(((const u16*)Ap)[idx]);
      }
      As[k][m] = v;
    }
#pragma unroll
    for (int u = 0; u < 8; ++u) {            // B tile: 16 x 128
      int i = tid + (u << 8);
      int k = i >> 7, n = i & 127;
      int gc = col0 + n;
      float v = 0.f;
      if (gc < N) {
        size_t idx = (size_t)(kt + k) * ldb + gc;
        v = BF ? ((const float*)Bp)[idx] : b2f(((const u16*)Bp)[idx]);
      }
      Bs[k][n] = v;
    }
    __syncthreads();
#pragma unroll
    for (int kk = 0; kk < 16; ++kk) {
      float a[8], b[8];
#pragma unroll
      for (int i = 0; i < 8; ++i) a[i] = As[kk][(ty << 3) + i];
#pragma unroll
      for (int j = 0; j < 8; ++j) b[j] = Bs[kk][(tx << 3) + j];
#pragma unroll
      for (int i = 0; i < 8; ++i)
#pragma unroll
        for (int j = 0; j < 8; ++j) acc[i][j] += a[i] * b[j];
    }
    __syncthreads();
  }

#pragma unroll
  for (int i = 0; i < 8; ++i) {
    int gr = row0 + (ty << 3) + i;
    if (gr >= M) continue;
#pragma unroll
    for (int j = 0; j < 8; ++j) {
      int gc = col0 + (tx << 3) + j;
      if (gc >= N) continue;
      float v = acc[i][j];
      if (biasF) v += biasF[gc];
      if (act) v = fmaxf(v, 0.f);
      if (CF) ((float*)Cp)[(size_t)gr * ldc + gc] = v;
      else    ((u16*)Cp)[(size_t)gr * ldc + gc] = f2b(v);
      if (C2) C2[(size_t)gr * ldc2 + gc] = v;
    }
  }
}

// ---------------------------------------------------------------------------
// Router attention (over batch axis): per workgroup = one (n_local, head).
// qkv chunk (bf16): [16*chunkN, 7680] rows r = l*chunkN + n_local. dh=640, L=16.
// obuf (bf16): [8192, 2560], row l*512 + n0 + n_local.
// ---------------------------------------------------------------------------
__global__ __launch_bounds__(256) void router_attn(
    const u16* __restrict__ qkv, u16* __restrict__ obuf, int n0, int chunkN)
{
  __shared__ float qs[16 * 640];
  __shared__ float ks[16 * 640];
  __shared__ float vs[16 * 640];
  __shared__ float S[16][16];
  const int tid = threadIdx.x;
  const int hh = blockIdx.x & 3, nl = blockIdx.x >> 2;

  for (int i = tid; i < 10240; i += 256) {
    int l = i / 640, d = i - l * 640;
    size_t r = ((size_t)(l * chunkN + nl)) * 7680 + hh * 640 + d;
    qs[i] = b2f(qkv[r]);
    ks[i] = b2f(qkv[r + 2560]);
    vs[i] = b2f(qkv[r + 5120]);
  }
  __syncthreads();
  {
    int l = tid >> 4, m = tid & 15;
    const float* ql = qs + l * 640;
    const float* km = ks + m * 640;
    float s = 0.f;
    for (int d = 0; d < 640; ++d) s += ql[d] * km[d];
    S[l][m] = s * 0.03952847075210474f;   // 1/sqrt(640)
  }
  __syncthreads();
  if (tid < 16) {
    float mx = -1e30f;
#pragma unroll
    for (int m = 0; m < 16; ++m) mx = fmaxf(mx, S[tid][m]);
    float sum = 0.f;
#pragma unroll
    for (int m = 0; m < 16; ++m) { float e = __expf(S[tid][m] - mx); S[tid][m] = e; sum += e; }
    float inv = 1.f / sum;
#pragma unroll
    for (int m = 0; m < 16; ++m) S[tid][m] *= inv;
  }
  __syncthreads();
  for (int i = tid; i < 10240; i += 256) {
    int l = i / 640, d = i - l * 640;
    float acc = 0.f;
#pragma unroll
    for (int m = 0; m < 16; ++m) acc += S[l][m] * vs[m * 640 + d];
    obuf[((size_t)(l * 512 + n0 + nl)) * 2560 + hh * 640 + d] = f2b(acc);
  }
}

// ---------------------------------------------------------------------------
// Formal-expert attention: per workgroup = one n. E=128, nh=4, dh=32, L=16.
// fqkv (bf16): [8192, 384] rows l*512+n. ofb (bf16): [8192,128].
// ---------------------------------------------------------------------------
__global__ __launch_bounds__(256) void formal_attn(
    const u16* __restrict__ fqkv, u16* __restrict__ ofb)
{
  __shared__ float fs[16 * 384];
  __shared__ float S[4][16][16];
  const int n = blockIdx.x, tid = threadIdx.x;

  for (int i = tid; i < 6144; i += 256) {
    int l = i / 384, c = i - l * 384;
    fs[i] = b2f(fqkv[((size_t)(l * 512 + n)) * 384 + c]);
  }
  __syncthreads();
  for (int t = tid; t < 1024; t += 256) {
    int h = t >> 8, l = (t >> 4) & 15, m = t & 15;
    float s = 0.f;
#pragma unroll
    for (int d = 0; d < 32; ++d)
      s += fs[l * 384 + h * 32 + d] * fs[m * 384 + 128 + h * 32 + d];
    S[h][l][m] = s * 0.17677669529663689f;   // 1/sqrt(32)
  }
  __syncthreads();
  if (tid < 64) {
    int h = tid >> 4, l = tid & 15;
    float mx = -1e30f;
#pragma unroll
    for (int m = 0; m < 16; ++m) mx = fmaxf(mx, S[h][l][m]);
    float sum = 0.f;
#pragma unroll
    for (int m = 0; m < 16; ++m) { float e = __expf(S[h][l][m] - mx); S[h][l][m] = e; sum += e; }
    float inv = 1.f / sum;
#pragma unroll
    for (int m = 0; m < 16; ++m) S[h][l][m] *= inv;
  }
  __syncthreads();
  for (int t = tid; t < 2048; t += 256) {
    int l = t >> 7, e = t & 127, h = e >> 5;
    float acc = 0.f;
#pragma unroll
    for (int m = 0; m < 16; ++m) acc += S[h][l][m] * fs[m * 384 + 256 + h * 32 + (e & 31)];
    ofb[((size_t)(l * 512 + n)) * 128 + e] = f2b(acc);
  }
}

// ---------------------------------------------------------------------------
// GAT prep: per row r: inv_norm(distilled), as1 = h.att_src, as2 = h.att_dst
// ---------------------------------------------------------------------------
__global__ __launch_bounds__(256) void gat_prep(
    const u16* __restrict__ dist, const u16* __restrict__ hbuf,
    const float* __restrict__ att_src, const float* __restrict__ att_dst,
    float* __restrict__ invn, float* __restrict__ as1, float* __restrict__ as2)
{
  int wid = threadIdx.x >> 6, lane = threadIdx.x & 63;
  int r = blockIdx.x * 4 + wid;
  const u16* dr = dist + (size_t)r * 128;
  const u16* hr = hbuf + (size_t)r * 128;
  float d0 = b2f(dr[lane]), d1 = b2f(dr[lane + 64]);
  float h0 = b2f(hr[lane]), h1 = b2f(hr[lane + 64]);
  float s0 = att_src[lane], s1 = att_src[lane + 64];
  float t0 = att_dst[lane], t1 = att_dst[lane + 64];
  float ss = d0 * d0 + d1 * d1;
  float a1 = h0 * s0 + h1 * s1;
  float a2 = h0 * t0 + h1 * t1;
#pragma unroll
  for (int off = 32; off > 0; off >>= 1) {
    ss += __shfl_down(ss, off, 64);
    a1 += __shfl_down(a1, off, 64);
    a2 += __shfl_down(a2, off, 64);
  }
  if (lane == 0) {
    invn[r] = 1.f / fmaxf(sqrtf(ss), 1e-12f);
    as1[r] = a1; as2[r] = a2;
  }
}

// ---------------------------------------------------------------------------
// GAT main: per workgroup = one (b, target j).
// ---------------------------------------------------------------------------
__global__ __launch_bounds__(256) void gat_main(
    const u16* __restrict__ dist, const u16* __restrict__ hbuf,
    const float* __restrict__ invn, const float* __restrict__ as1,
    const float* __restrict__ as2, const float* __restrict__ gat_b,
    u16* __restrict__ gato)
{
  __shared__ float dj[128];
  __shared__ float val[512];
  __shared__ float red[8];
  const int b = blockIdx.x >> 9, j = blockIdx.x & 511;
  const int tid = threadIdx.x;
  const size_t rj = (size_t)b * 512 + j;

  if (tid < 128) dj[tid] = b2f(dist[rj * 128 + tid]) * invn[rj];
  __syncthreads();

  const float a2j = as2[rj];
  for (int ii = tid; ii < 512; ii += 256) {
    const u16* di = dist + ((size_t)b * 512 + ii) * 128;
    float dot = 0.f;
#pragma unroll
    for (int k2 = 0; k2 < 128; ++k2) dot += b2f(di[k2]) * dj[k2];
    float cosv = dot * invn[(size_t)b * 512 + ii];
    bool adjf = (ii == j) || ((ii < j) && (cosv > 0.9f));
    float xx = as1[(size_t)b * 512 + ii] + a2j;
    float e = (xx >= 0.f) ? xx : 0.2f * xx;
    val[ii] = adjf ? e : -1e9f;
  }
  __syncthreads();

  float v = fmaxf(val[tid], val[tid + 256]);
#pragma unroll
  for (int off = 32; off > 0; off >>= 1) v = fmaxf(v, __shfl_down(v, off, 64));
  if ((tid & 63) == 0) red[tid >> 6] = v;
  __syncthreads();
  const float mx = fmaxf(fmaxf(red[0], red[1]), fmaxf(red[2], red[3]));

  float s = 0.f;
  for (int ii = tid; ii < 512; ii += 256) {
    float e = __expf(val[ii] - mx);
    val[ii] = e; s += e;
  }
#pragma unroll
  for (int off = 32; off > 0; off >>= 1) s += __shfl_down(s, off, 64);
  if ((tid & 63) == 0) red[4 + (tid >> 6)] = s;
  __syncthreads();
  const float inv = 1.f / (red[4] + red[5] + red[6] + red[7]);

  if (tid < 128) {
    float acc = 0.f;
    const u16* hb = hbuf + (size_t)b * 512 * 128;
    for (int ii = 0; ii < 512; ++ii) acc += val[ii] * b2f(hb[ii * 128 + tid]);
    float res = acc * inv + gat_b[tid];
    gato[rj * 128 + tid] = f2b(fmaxf(res, 0.f));
  }
}

// ---------------------------------------------------------------------------
// Small helper kernels (all-fp32 weights now)
// ---------------------------------------------------------------------------
__global__ void build_mix(const float* __restrict__ dyn,
                          const float* __restrict__ dW0, const float* __restrict__ dW1,
                          const float* __restrict__ dW2, const float* __restrict__ db0,
                          const float* __restrict__ db1, const float* __restrict__ db2,
                          float* __restrict__ Wmix, float* __restrict__ bmix)
{
  int idx = blockIdx.x * 256 + threadIdx.x;
  float c[3];
#pragma unroll
  for (int m = 0; m < 3; ++m) c[m] = dyn[0 * 3 + m] + dyn[1 * 3 + m] + dyn[2 * 3 + m];
  if (idx < 384 * 128) {
    int r = idx >> 7, col = idx & 127;
    int m = r >> 7, rr = r & 127;
    const float* dW = (m == 0) ? dW0 : ((m == 1) ? dW1 : dW2);
    Wmix[idx] = c[m] * dW[rr * 128 + col];
  }
  if (idx < 128)
    bmix[idx] = c[0] * db0[idx] + c[1] * db1[idx] + c[2] * db2[idx];
}

// out[j] = sum_e vb[e]*W[e,j] + b1[j]
__global__ void bias_fold(const float* __restrict__ vb, const float* __restrict__ W,
                          const float* __restrict__ b1, float* __restrict__ outp,
                          int K, int N)
{
  int j = blockIdx.x * 256 + threadIdx.x;
  if (j >= N) return;
  float s = 0.f;
  for (int e = 0; e < K; ++e) s += vb[e] * W[(size_t)e * N + j];
  outp[j] = s + b1[j];
}

// route[r] = sigmoid(z1[r,:].r_f2w + r_f2b)
__global__ __launch_bounds__(256) void route_kernel(
    const u16* __restrict__ z1, const float* __restrict__ r_f2w,
    const float* __restrict__ r_f2b, float* __restrict__ routeF,
    float* __restrict__ route_out)
{
  int wid = threadIdx.x >> 6, lane = threadIdx.x & 63;
  int r = blockIdx.x * 4 + wid;
  const u16* zr = z1 + (size_t)r * 128;
  float v = b2f(zr[lane]) * r_f2w[lane] + b2f(zr[lane + 64]) * r_f2w[lane + 64];
#pragma unroll
  for (int off = 32; off > 0; off >>= 1) v += __shfl_down(v, off, 64);
  if (lane == 0) {
    float x = v + r_f2b[0];
    float sg = 1.f / (1.f + __expf(-x));
    routeF[r] = sg;
    route_out[r] = sg;
  }
}

__global__ void combine_kernel(const float* __restrict__ routeF,
                               const u16* __restrict__ outf, const u16* __restrict__ outi,
                               float* __restrict__ outp)
{
  size_t idx = (size_t)blockIdx.x * 256 + threadIdx.x;   // 8192*128 exact
  float rt = routeF[idx >> 7];
  outp[idx] = rt * b2f(outf[idx]) + (1.f - rt) * b2f(outi[idx]);
}

// ---------------------------------------------------------------------------
extern "C" void kernel_launch(void* const* d_in, const int* in_sizes, int n_in,
                              void* d_out, int out_size, void* d_ws, size_t ws_size,
                              hipStream_t stream)
{
  const float* x0 = (const float*)d_in[0];
  const float* x1 = (const float*)d_in[1];
  const float* x2 = (const float*)d_in[2];
  const float* ctx = (const float*)d_in[3];
  const float* sW[3] = {(const float*)d_in[4], (const float*)d_in[10], (const float*)d_in[16]};
  const float* sb[3] = {(const float*)d_in[5], (const float*)d_in[11], (const float*)d_in[17]};
  const float* pW[3] = {(const float*)d_in[6], (const float*)d_in[12], (const float*)d_in[18]};
  const float* pb[3] = {(const float*)d_in[7], (const float*)d_in[13], (const float*)d_in[19]};
  const float* dW[3] = {(const float*)d_in[8], (const float*)d_in[14], (const float*)d_in[20]};
  const float* db[3] = {(const float*)d_in[9], (const float*)d_in[15], (const float*)d_in[21]};
  const float* dyn_w = (const float*)d_in[22];
  const float* doW = (const float*)d_in[23];
  const float* dob = (const float*)d_in[24];
  const float* gatW = (const float*)d_in[25];
  const float* att_src = (const float*)d_in[26];
  const float* att_dst = (const float*)d_in[27];
  const float* gat_b = (const float*)d_in[28];
  const float* r_qkv_w = (const float*)d_in[29];
  const float* r_qkv_b = (const float*)d_in[30];
  const float* r_out_w = (const float*)d_in[31];
  const float* r_out_b = (const float*)d_in[32];
  const float* r_f1w = (const float*)d_in[33];
  const float* r_f1b = (const float*)d_in[34];
  const float* r_f2w = (const float*)d_in[35];
  const float* r_f2b = (const float*)d_in[36];
  const float* f_qkv_w = (const float*)d_in[37];
  const float* f_qkv_b = (const float*)d_in[38];
  const float* f_out_w = (const float*)d_in[39];
  const float* f_out_b = (const float*)d_in[40];
  const float* f_f1w = (const float*)d_in[41];
  const float* f_f1b = (const float*)d_in[42];
  const float* f_f2w = (const float*)d_in[43];
  const float* f_f2b = (const float*)d_in[44];
  const float* i_f1w = (const float*)d_in[45];
  const float* i_f1b = (const float*)d_in[46];
  const float* i_f2w = (const float*)d_in[47];
  const float* i_f2b = (const float*)d_in[48];
  (void)in_sizes; (void)n_in; (void)out_size; (void)ws_size;

  float* out = (float*)d_out;
  const size_t off_route = 1048576, off_sh0 = 1056768, off_sh1 = 2105344,
               off_sh2 = 3153920, off_p0 = 4202496, off_p1 = 5251072,
               off_p2 = 6299648, off_dist = 7348224;

  char* wsb = (char*)d_ws;
  size_t wo = 0;
  auto alloc = [&](size_t bytes) -> void* {
    void* p = wsb + wo;
    wo += (bytes + 255) & ~(size_t)255;
    return p;
  };
  u16* shcat = (u16*)alloc((size_t)8192 * 384 * 2);
  u16* tbuf  = (u16*)alloc((size_t)8192 * 128 * 2);
  u16* dist  = (u16*)alloc((size_t)8192 * 128 * 2);
  u16* hbuf  = (u16*)alloc((size_t)8192 * 128 * 2);
  u16* gato  = (u16*)alloc((size_t)8192 * 128 * 2);
  float* invn = (float*)alloc(8192 * 4);
  float* as1b = (float*)alloc(8192 * 4);
  float* as2b = (float*)alloc(8192 * 4);
  float* Wmix = (float*)alloc(384 * 128 * 4);
  float* bmix = (float*)alloc(128 * 4);
  u16* WrP = (u16*)alloc((size_t)2560 * 128 * 2);
  float* brP = (float*)alloc(128 * 4);
  u16* WfP = (u16*)alloc((size_t)128 * 512 * 2);
  float* bfP = (float*)alloc(512 * 4);
  u16* qkvc = (u16*)alloc((size_t)2048 * 7680 * 2);
  u16* obuf = (u16*)alloc((size_t)8192 * 2560 * 2);
  u16* z1   = (u16*)alloc((size_t)8192 * 128 * 2);
  float* routeF = (float*)alloc(8192 * 4);
  u16* fqkv = (u16*)alloc((size_t)8192 * 384 * 2);
  u16* ofb  = (u16*)alloc((size_t)8192 * 128 * 2);
  u16* hidf = (u16*)alloc((size_t)8192 * 512 * 2);
  u16* outf = (u16*)alloc((size_t)8192 * 128 * 2);
  u16* hidi = (u16*)alloc((size_t)8192 * 512 * 2);
  u16* outi = (u16*)alloc((size_t)8192 * 128 * 2);

  // --- weight folds ---
  build_mix<<<192, 256, 0, stream>>>(dyn_w, dW[0], dW[1], dW[2], db[0], db[1], db[2], Wmix, bmix);
  bias_fold<<<1, 256, 0, stream>>>(r_out_b, r_f1w, r_f1b, brP, 2560, 128);
  bias_fold<<<2, 256, 0, stream>>>(f_out_b, f_f1w, f_f1b, bfP, 128, 512);
  gemm_t<1,1,0><<<dim3(1, 20), 256, 0, stream>>>(r_out_w, 2560, r_f1w, 128, nullptr,
      WrP, 128, nullptr, 0, 2560, 128, 2560, 0, -1, 0, 0);
  gemm_t<1,1,0><<<dim3(4, 1), 256, 0, stream>>>(f_out_w, 128, f_f1w, 512, nullptr,
      WfP, 512, nullptr, 0, 128, 512, 128, 0, -1, 0, 0);

  // --- feature decoupler ---
  gemm_t<1,1,0><<<dim3(1, 64), 256, 0, stream>>>(x0, 512, sW[0], 128, sb[0],
      shcat + 0, 384, out + off_sh0, 128, 8192, 128, 512, 0, -1, 0, 0);
  gemm_t<1,1,0><<<dim3(1, 64), 256, 0, stream>>>(x1, 1024, sW[1], 128, sb[1],
      shcat + 128, 384, out + off_sh1, 128, 8192, 128, 1024, 0, -1, 0, 0);
  gemm_t<1,1,0><<<dim3(1, 64), 256, 0, stream>>>(x2, 1024, sW[2], 128, sb[2],
      shcat + 256, 384, out + off_sh2, 128, 8192, 128, 1024, 0, -1, 0, 0);
  gemm_t<1,1,1><<<dim3(1, 64), 256, 0, stream>>>(x0, 512, pW[0], 128, pb[0],
      out + off_p0, 128, nullptr, 0, 8192, 128, 512, 0, -1, 0, 0);
  gemm_t<1,1,1><<<dim3(1, 64), 256, 0, stream>>>(x1, 1024, pW[1], 128, pb[1],
      out + off_p1, 128, nullptr, 0, 8192, 128, 1024, 0, -1, 0, 0);
  gemm_t<1,1,1><<<dim3(1, 64), 256, 0, stream>>>(x2, 1024, pW[2], 128, pb[2],
      out + off_p2, 128, nullptr, 0, 8192, 128, 1024, 0, -1, 0, 0);

  // --- distiller ---
  gemm_t<0,1,0><<<dim3(1, 64), 256, 0, stream>>>(shcat, 384, Wmix, 128, bmix,
      tbuf, 128, nullptr, 0, 8192, 128, 384, 0, -1, 0, 0);
  gemm_t<0,1,0><<<dim3(1, 64), 256, 0, stream>>>(tbuf, 128, doW, 128, dob,
      dist, 128, out + off_dist, 128, 8192, 128, 128, 0, -1, 0, 0);

  // --- GAT ---
  gemm_t<0,1,0><<<dim3(1, 64), 256, 0, stream>>>(dist, 128, gatW, 128, nullptr,
      hbuf, 128, nullptr, 0, 8192, 128, 128, 0, -1, 0, 0);
  gat_prep<<<2048, 256, 0, stream>>>(dist, hbuf, att_src, att_dst, invn, as1b, as2b);
  gat_main<<<8192, 256, 0, stream>>>(dist, hbuf, invn, as1b, as2b, gat_b, gato);

  // --- router: qkv + attention over batch axis, n-chunked ---
  for (int c = 0; c < 4; ++c) {
    gemm_t<1,1,0><<<dim3(60, 16), 256, 0, stream>>>(ctx, 2560, r_qkv_w, 7680, r_qkv_b,
        qkvc, 7680, nullptr, 0, 2048, 7680, 2560, 0, /*map_shift=*/7, /*n0=*/c * 128, /*smap=*/512);
    router_attn<<<512, 256, 0, stream>>>(qkvc, obuf, c * 128, 128);
  }
  gemm_t<0,0,0><<<dim3(1, 64), 256, 0, stream>>>(obuf, 2560, WrP, 128, brP,
      z1, 128, nullptr, 0, 8192, 128, 2560, 1, -1, 0, 0);
  route_kernel<<<2048, 256, 0, stream>>>(z1, r_f2w, r_f2b, routeF, out + off_route);

  // --- formal expert ---
  gemm_t<0,1,0><<<dim3(3, 64), 256, 0, stream>>>(gato, 128, f_qkv_w, 384, f_qkv_b,
      fqkv, 384, nullptr, 0, 8192, 384, 128, 0, -1, 0, 0);
  formal_attn<<<512, 256, 0, stream>>>(fqkv, ofb);
  gemm_t<0,0,0><<<dim3(4, 64), 256, 0, stream>>>(ofb, 128, WfP, 512, bfP,
      hidf, 512, nullptr, 0, 8192, 512, 128, 1, -1, 0, 0);
  gemm_t<0,1,0><<<dim3(1, 64), 256, 0, stream>>>(hidf, 512, f_f2w, 128, f_f2b,
      outf, 128, nullptr, 0, 8192, 128, 512, 0, -1, 0, 0);

  // --- informal expert ---
  gemm_t<0,1,0><<<dim3(4, 64), 256, 0, stream>>>(gato, 128, i_f1w, 512, i_f1b,
      hidi, 512, nullptr, 0, 8192, 512, 128, 1, -1, 0, 0);
  gemm_t<0,1,0><<<dim3(1, 64), 256, 0, stream>>>(hidi, 512, i_f2w, 128, i_f2b,
      outi, 128, nullptr, 0, 8192, 128, 512, 0, -1, 0, 0);

  // --- mix ---
  combine_kernel<<<4096, 256, 0, stream>>>(routeF, outf, outi, out);
}

// Round 3
// 3127.341 us; speedup vs baseline: 3.8543x; 3.8543x over previous
//
#include <hip/hip_runtime.h>

typedef unsigned short u16;
typedef __attribute__((ext_vector_type(4))) float f32x4;
typedef __attribute__((ext_vector_type(8))) short bf16x8;

__device__ __forceinline__ float b2f(u16 u) {
  unsigned int x = ((unsigned int)u) << 16;
  float f; __builtin_memcpy(&f, &x, 4); return f;
}
__device__ __forceinline__ u16 f2b(float f) {
  unsigned int x; __builtin_memcpy(&x, &f, 4);
  unsigned int r = x + 0x7fffu + ((x >> 16) & 1u);
  return (u16)(r >> 16);
}

__device__ __forceinline__ void async_cp16(const void* g, void* l) {
  __builtin_amdgcn_global_load_lds(
      (const __attribute__((address_space(1))) void*)g,
      (__attribute__((address_space(3))) void*)l, 16, 0, 0);
}

// ---------------------------------------------------------------------------
// MFMA bf16 GEMM, m97 structure: 128x128 tile, BK=32, 4 waves (2x2), each wave
// 4x4 tiles of 16x16x32. A [M][lda] bf16 row-major; Bt [N][ldb] bf16 (B^T).
// C bf16 (optional), C2 fp32 (optional). Requires M%128==0, N%128==0, K%32==0.
// Output row remap (z1 chunks): phys = (r>>oshift)*512 + on0 + (r & mask).
// ---------------------------------------------------------------------------
__global__ __launch_bounds__(256) void gemm_mfma(
    const u16* __restrict__ A, int lda,
    const u16* __restrict__ Bt, int ldb,
    const float* __restrict__ biasF,
    u16* __restrict__ C, int ldc,
    float* __restrict__ C2, int ldc2,
    int K, int act, int oshift, int on0)
{
  __shared__ u16 As[128 * 32];
  __shared__ u16 Bs[128 * 32];
  const int tid = threadIdx.x, lane = tid & 63, w = tid >> 6;
  const int wm = w >> 1, wn = w & 1;
  const int row0 = blockIdx.y << 7, col0 = blockIdx.x << 7;

  f32x4 acc[4][4] = {};

  const int srow = w * 32 + (lane >> 2);     // staging row (+16 for 2nd inst)
  const int scol = (lane & 3) * 8;
  const u16* ga = A + (size_t)(row0 + srow) * lda + scol;
  const u16* gb = Bt + (size_t)(col0 + srow) * ldb + scol;
  u16* la = As + w * 1024;                   // wave-uniform LDS base
  u16* lb = Bs + w * 1024;

  const int mrow = lane & 15;
  const int koff = (lane >> 4) * 8;

  for (int kt = 0; kt < K; kt += 32) {
    async_cp16(ga, la);
    async_cp16(ga + (size_t)16 * lda, la + 512);
    async_cp16(gb, lb);
    async_cp16(gb + (size_t)16 * ldb, lb + 512);
    ga += 32; gb += 32;
    __syncthreads();

    bf16x8 af[4], bf[4];
#pragma unroll
    for (int t = 0; t < 4; ++t) {
      af[t] = *(const bf16x8*)(As + (wm * 64 + t * 16 + mrow) * 32 + koff);
      bf[t] = *(const bf16x8*)(Bs + (wn * 64 + t * 16 + mrow) * 32 + koff);
    }
#pragma unroll
    for (int tm = 0; tm < 4; ++tm)
#pragma unroll
      for (int tn = 0; tn < 4; ++tn)
        acc[tm][tn] = __builtin_amdgcn_mfma_f32_16x16x32_bf16(af[tm], bf[tn], acc[tm][tn], 0, 0, 0);
    __syncthreads();
  }

  const int crow = (lane >> 4) * 4;
  const int ccol = lane & 15;
#pragma unroll
  for (int tm = 0; tm < 4; ++tm) {
#pragma unroll
    for (int tn = 0; tn < 4; ++tn) {
      const int gc = col0 + wn * 64 + tn * 16 + ccol;
      const float bias = biasF ? biasF[gc] : 0.f;
#pragma unroll
      for (int r = 0; r < 4; ++r) {
        int grl = row0 + wm * 64 + tm * 16 + crow + r;
        int gr = grl;
        if (oshift >= 0)
          gr = ((grl >> oshift) * 512) + on0 + (grl & ((1 << oshift) - 1));
        float v = acc[tm][tn][r] + bias;
        if (act) v = fmaxf(v, 0.f);
        if (C)  C[(size_t)gr * ldc + gc] = f2b(v);
        if (C2) C2[(size_t)gr * ldc2 + gc] = v;
      }
    }
  }
}

// ---------------------------------------------------------------------------
// fp32 -> bf16 elementwise (n4 = n/4)
// ---------------------------------------------------------------------------
__global__ void f2b_copy(const float* __restrict__ in, u16* __restrict__ out, int n4)
{
  int i = blockIdx.x * 256 + threadIdx.x;
  if (i < n4) {
    float4 v = ((const float4*)in)[i];
    ushort4 o; o.x = f2b(v.x); o.y = f2b(v.y); o.z = f2b(v.z); o.w = f2b(v.w);
    ((ushort4*)out)[i] = o;
  }
}

// fp32 [R][C] -> bf16 [C][R]
__global__ __launch_bounds__(256) void transpose_f2b(
    const float* __restrict__ in, u16* __restrict__ out, int R, int C)
{
  __shared__ float t[32][33];
  const int bx = blockIdx.x * 32, by = blockIdx.y * 32;
  const int x = threadIdx.x & 31, y = threadIdx.x >> 5;   // 32 x 8
#pragma unroll
  for (int i = 0; i < 32; i += 8) {
    int r = by + y + i, c = bx + x;
    t[y + i][x] = (r < R && c < C) ? in[(size_t)r * C + c] : 0.f;
  }
  __syncthreads();
#pragma unroll
  for (int i = 0; i < 32; i += 8) {
    int r = bx + y + i, c = by + x;
    if (r < C && c < R) out[(size_t)r * R + c] = f2b(t[x][y + i]);
  }
}

// gather ctx rows for router chunk: dst[(l*64+nl)][d] = ctx[(l*512+n0+nl)][d]
__global__ void gather_f2b(const float* __restrict__ src, u16* __restrict__ dst, int n0)
{
  int idx = blockIdx.x * 256 + threadIdx.x;   // over 1024*640 float4s
  int r = idx / 640, d = (idx - r * 640) * 4;
  int pr = ((r >> 6) * 512) + n0 + (r & 63);
  float4 v = *(const float4*)(src + (size_t)pr * 2560 + d);
  ushort4 o; o.x = f2b(v.x); o.y = f2b(v.y); o.z = f2b(v.z); o.w = f2b(v.w);
  *(ushort4*)(dst + (size_t)r * 2560 + d) = o;
}

// ---------------------------------------------------------------------------
// Router attention: per workgroup = one (nl, head). qkv chunk [16*64, 7680]
// rows r = l*64 + nl. Writes chunk-local obuf_c [1024][2560].
// ---------------------------------------------------------------------------
__global__ __launch_bounds__(256) void router_attn(
    const u16* __restrict__ qkv, u16* __restrict__ obufc)
{
  __shared__ float qs[16 * 640];
  __shared__ float ks[16 * 640];
  __shared__ float vs[16 * 640];
  __shared__ float S[16][16];
  const int tid = threadIdx.x;
  const int hh = blockIdx.x & 3, nl = blockIdx.x >> 2;

  for (int i = tid; i < 10240; i += 256) {
    int l = i / 640, d = i - l * 640;
    size_t r = ((size_t)(l * 64 + nl)) * 7680 + hh * 640 + d;
    qs[i] = b2f(qkv[r]);
    ks[i] = b2f(qkv[r + 2560]);
    vs[i] = b2f(qkv[r + 5120]);
  }
  __syncthreads();
  {
    int l = tid >> 4, m = tid & 15;
    const float* ql = qs + l * 640;
    const float* km = ks + m * 640;
    float s = 0.f;
    for (int d = 0; d < 640; ++d) s += ql[d] * km[d];
    S[l][m] = s * 0.03952847075210474f;   // 1/sqrt(640)
  }
  __syncthreads();
  if (tid < 16) {
    float mx = -1e30f;
#pragma unroll
    for (int m = 0; m < 16; ++m) mx = fmaxf(mx, S[tid][m]);
    float sum = 0.f;
#pragma unroll
    for (int m = 0; m < 16; ++m) { float e = __expf(S[tid][m] - mx); S[tid][m] = e; sum += e; }
    float inv = 1.f / sum;
#pragma unroll
    for (int m = 0; m < 16; ++m) S[tid][m] *= inv;
  }
  __syncthreads();
  for (int i = tid; i < 10240; i += 256) {
    int l = i / 640, d = i - l * 640;
    float acc = 0.f;
#pragma unroll
    for (int m = 0; m < 16; ++m) acc += S[l][m] * vs[m * 640 + d];
    obufc[((size_t)(l * 64 + nl)) * 2560 + hh * 640 + d] = f2b(acc);
  }
}

// ---------------------------------------------------------------------------
// Formal-expert attention: per workgroup = one n. E=128, nh=4, dh=32, L=16.
// ---------------------------------------------------------------------------
__global__ __launch_bounds__(256) void formal_attn(
    const u16* __restrict__ fqkv, u16* __restrict__ ofb)
{
  __shared__ float fs[16 * 384];
  __shared__ float S[4][16][16];
  const int n = blockIdx.x, tid = threadIdx.x;

  for (int i = tid; i < 6144; i += 256) {
    int l = i / 384, c = i - l * 384;
    fs[i] = b2f(fqkv[((size_t)(l * 512 + n)) * 384 + c]);
  }
  __syncthreads();
  for (int t = tid; t < 1024; t += 256) {
    int h = t >> 8, l = (t >> 4) & 15, m = t & 15;
    float s = 0.f;
#pragma unroll
    for (int d = 0; d < 32; ++d)
      s += fs[l * 384 + h * 32 + d] * fs[m * 384 + 128 + h * 32 + d];
    S[h][l][m] = s * 0.17677669529663689f;   // 1/sqrt(32)
  }
  __syncthreads();
  if (tid < 64) {
    int h = tid >> 4, l = tid & 15;
    float mx = -1e30f;
#pragma unroll
    for (int m = 0; m < 16; ++m) mx = fmaxf(mx, S[h][l][m]);
    float sum = 0.f;
#pragma unroll
    for (int m = 0; m < 16; ++m) { float e = __expf(S[h][l][m] - mx); S[h][l][m] = e; sum += e; }
    float inv = 1.f / sum;
#pragma unroll
    for (int m = 0; m < 16; ++m) S[h][l][m] *= inv;
  }
  __syncthreads();
  for (int t = tid; t < 2048; t += 256) {
    int l = t >> 7, e = t & 127, h = e >> 5;
    float acc = 0.f;
#pragma unroll
    for (int m = 0; m < 16; ++m) acc += S[h][l][m] * fs[m * 384 + 256 + h * 32 + (e & 31)];
    ofb[((size_t)(l * 512 + n)) * 128 + e] = f2b(acc);
  }
}

// ---------------------------------------------------------------------------
// GAT prep
// ---------------------------------------------------------------------------
__global__ __launch_bounds__(256) void gat_prep(
    const u16* __restrict__ dist, const u16* __restrict__ hbuf,
    const float* __restrict__ att_src, const float* __restrict__ att_dst,
    float* __restrict__ invn, float* __restrict__ as1, float* __restrict__ as2)
{
  int wid = threadIdx.x >> 6, lane = threadIdx.x & 63;
  int r = blockIdx.x * 4 + wid;
  const u16* dr = dist + (size_t)r * 128;
  const u16* hr = hbuf + (size_t)r * 128;
  float d0 = b2f(dr[lane]), d1 = b2f(dr[lane + 64]);
  float h0 = b2f(hr[lane]), h1 = b2f(hr[lane + 64]);
  float s0 = att_src[lane], s1 = att_src[lane + 64];
  float t0 = att_dst[lane], t1 = att_dst[lane + 64];
  float ss = d0 * d0 + d1 * d1;
  float a1 = h0 * s0 + h1 * s1;
  float a2 = h0 * t0 + h1 * t1;
#pragma unroll
  for (int off = 32; off > 0; off >>= 1) {
    ss += __shfl_down(ss, off, 64);
    a1 += __shfl_down(a1, off, 64);
    a2 += __shfl_down(a2, off, 64);
  }
  if (lane == 0) {
    invn[r] = 1.f / fmaxf(sqrtf(ss), 1e-12f);
    as1[r] = a1; as2[r] = a2;
  }
}

// ---------------------------------------------------------------------------
// GAT main: per workgroup = one (b, target j).
// ---------------------------------------------------------------------------
__global__ __launch_bounds__(256) void gat_main(
    const u16* __restrict__ dist, const u16* __restrict__ hbuf,
    const float* __restrict__ invn, const float* __restrict__ as1,
    const float* __restrict__ as2, const float* __restrict__ gat_b,
    u16* __restrict__ gato)
{
  __shared__ float dj[128];
  __shared__ float val[512];
  __shared__ float red[8];
  const int b = blockIdx.x >> 9, j = blockIdx.x & 511;
  const int tid = threadIdx.x;
  const size_t rj = (size_t)b * 512 + j;

  if (tid < 128) dj[tid] = b2f(dist[rj * 128 + tid]) * invn[rj];
  __syncthreads();

  const float a2j = as2[rj];
  for (int ii = tid; ii < 512; ii += 256) {
    const u16* di = dist + ((size_t)b * 512 + ii) * 128;
    float dot = 0.f;
#pragma unroll
    for (int k2 = 0; k2 < 128; ++k2) dot += b2f(di[k2]) * dj[k2];
    float cosv = dot * invn[(size_t)b * 512 + ii];
    bool adjf = (ii == j) || ((ii < j) && (cosv > 0.9f));
    float xx = as1[(size_t)b * 512 + ii] + a2j;
    float e = (xx >= 0.f) ? xx : 0.2f * xx;
    val[ii] = adjf ? e : -1e9f;
  }
  __syncthreads();

  float v = fmaxf(val[tid], val[tid + 256]);
#pragma unroll
  for (int off = 32; off > 0; off >>= 1) v = fmaxf(v, __shfl_down(v, off, 64));
  if ((tid & 63) == 0) red[tid >> 6] = v;
  __syncthreads();
  const float mx = fmaxf(fmaxf(red[0], red[1]), fmaxf(red[2], red[3]));

  float s = 0.f;
  for (int ii = tid; ii < 512; ii += 256) {
    float e = __expf(val[ii] - mx);
    val[ii] = e; s += e;
  }
#pragma unroll
  for (int off = 32; off > 0; off >>= 1) s += __shfl_down(s, off, 64);
  if ((tid & 63) == 0) red[4 + (tid >> 6)] = s;
  __syncthreads();
  const float inv = 1.f / (red[4] + red[5] + red[6] + red[7]);

  if (tid < 128) {
    float acc = 0.f;
    const u16* hb = hbuf + (size_t)b * 512 * 128;
    for (int ii = 0; ii < 512; ++ii) acc += val[ii] * b2f(hb[ii * 128 + tid]);
    float res = acc * inv + gat_b[tid];
    gato[rj * 128 + tid] = f2b(fmaxf(res, 0.f));
  }
}

// ---------------------------------------------------------------------------
// Small helpers
// ---------------------------------------------------------------------------
// WmixT bf16 [128][384]: WmixT[n][m*128+rr] = c[m]*dW_m[rr][n]; bmix fp32
__global__ void build_mix(const float* __restrict__ dyn,
                          const float* __restrict__ dW0, const float* __restrict__ dW1,
                          const float* __restrict__ dW2, const float* __restrict__ db0,
                          const float* __restrict__ db1, const float* __restrict__ db2,
                          u16* __restrict__ WmixT, float* __restrict__ bmix)
{
  int idx = blockIdx.x * 256 + threadIdx.x;
  float c[3];
#pragma unroll
  for (int m = 0; m < 3; ++m) c[m] = dyn[0 * 3 + m] + dyn[1 * 3 + m] + dyn[2 * 3 + m];
  if (idx < 128 * 384) {
    int n = idx / 384, k = idx - n * 384;
    int m = k >> 7, rr = k & 127;
    const float* dW = (m == 0) ? dW0 : ((m == 1) ? dW1 : dW2);
    WmixT[idx] = f2b(c[m] * dW[rr * 128 + n]);
  }
  if (idx < 128)
    bmix[idx] = c[0] * db0[idx] + c[1] * db1[idx] + c[2] * db2[idx];
}

__global__ void bias_fold(const float* __restrict__ vb, const float* __restrict__ W,
                          const float* __restrict__ b1, float* __restrict__ outp,
                          int K, int N)
{
  int j = blockIdx.x * 256 + threadIdx.x;
  if (j >= N) return;
  float s = 0.f;
  for (int e = 0; e < K; ++e) s += vb[e] * W[(size_t)e * N + j];
  outp[j] = s + b1[j];
}

__global__ __launch_bounds__(256) void route_kernel(
    const u16* __restrict__ z1, const float* __restrict__ r_f2w,
    const float* __restrict__ r_f2b, float* __restrict__ routeF,
    float* __restrict__ route_out)
{
  int wid = threadIdx.x >> 6, lane = threadIdx.x & 63;
  int r = blockIdx.x * 4 + wid;
  const u16* zr = z1 + (size_t)r * 128;
  float v = b2f(zr[lane]) * r_f2w[lane] + b2f(zr[lane + 64]) * r_f2w[lane + 64];
#pragma unroll
  for (int off = 32; off > 0; off >>= 1) v += __shfl_down(v, off, 64);
  if (lane == 0) {
    float x = v + r_f2b[0];
    float sg = 1.f / (1.f + __expf(-x));
    routeF[r] = sg;
    route_out[r] = sg;
  }
}

__global__ void combine_kernel(const float* __restrict__ routeF,
                               const u16* __restrict__ outf, const u16* __restrict__ outi,
                               float* __restrict__ outp)
{
  size_t idx = (size_t)blockIdx.x * 256 + threadIdx.x;
  float rt = routeF[idx >> 7];
  outp[idx] = rt * b2f(outf[idx]) + (1.f - rt) * b2f(outi[idx]);
}

// ---------------------------------------------------------------------------
extern "C" void kernel_launch(void* const* d_in, const int* in_sizes, int n_in,
                              void* d_out, int out_size, void* d_ws, size_t ws_size,
                              hipStream_t stream)
{
  const float* x0 = (const float*)d_in[0];
  const float* x1 = (const float*)d_in[1];
  const float* x2 = (const float*)d_in[2];
  const float* ctx = (const float*)d_in[3];
  const float* sW[3] = {(const float*)d_in[4], (const float*)d_in[10], (const float*)d_in[16]};
  const float* sb[3] = {(const float*)d_in[5], (const float*)d_in[11], (const float*)d_in[17]};
  const float* pW[3] = {(const float*)d_in[6], (const float*)d_in[12], (const float*)d_in[18]};
  const float* pb[3] = {(const float*)d_in[7], (const float*)d_in[13], (const float*)d_in[19]};
  const float* dW[3] = {(const float*)d_in[8], (const float*)d_in[14], (const float*)d_in[20]};
  const float* db[3] = {(const float*)d_in[9], (const float*)d_in[15], (const float*)d_in[21]};
  const float* dyn_w = (const float*)d_in[22];
  const float* doW = (const float*)d_in[23];
  const float* dob = (const float*)d_in[24];
  const float* gatW = (const float*)d_in[25];
  const float* att_src = (const float*)d_in[26];
  const float* att_dst = (const float*)d_in[27];
  const float* gat_b = (const float*)d_in[28];
  const float* r_qkv_w = (const float*)d_in[29];
  const float* r_qkv_b = (const float*)d_in[30];
  const float* r_out_w = (const float*)d_in[31];
  const float* r_out_b = (const float*)d_in[32];
  const float* r_f1w = (const float*)d_in[33];
  const float* r_f1b = (const float*)d_in[34];
  const float* r_f2w = (const float*)d_in[35];
  const float* r_f2b = (const float*)d_in[36];
  const float* f_qkv_w = (const float*)d_in[37];
  const float* f_qkv_b = (const float*)d_in[38];
  const float* f_out_w = (const float*)d_in[39];
  const float* f_out_b = (const float*)d_in[40];
  const float* f_f1w = (const float*)d_in[41];
  const float* f_f1b = (const float*)d_in[42];
  const float* f_f2w = (const float*)d_in[43];
  const float* f_f2b = (const float*)d_in[44];
  const float* i_f1w = (const float*)d_in[45];
  const float* i_f1b = (const float*)d_in[46];
  const float* i_f2w = (const float*)d_in[47];
  const float* i_f2b = (const float*)d_in[48];
  (void)in_sizes; (void)n_in; (void)out_size; (void)ws_size;

  float* out = (float*)d_out;
  const size_t off_route = 1048576, off_sh0 = 1056768, off_sh1 = 2105344,
               off_sh2 = 3153920, off_p0 = 4202496, off_p1 = 5251072,
               off_p2 = 6299648, off_dist = 7348224;

  char* wsb = (char*)d_ws;
  size_t wo = 0;
  auto alloc = [&](size_t bytes) -> void* {
    void* p = wsb + wo;
    wo += (bytes + 255) & ~(size_t)255;
    return p;
  };
  u16* r_qkv_wT = (u16*)alloc((size_t)7680 * 2560 * 2);      // 39.3 MB
  char* A2 = (char*)alloc((size_t)31457280);                 // arena: r_out_wB | qkvc | experts
  u16* xb   = (u16*)alloc((size_t)8192 * 1024 * 2);          // 16.8 MB
  u16* ctxb = (u16*)alloc((size_t)1024 * 2560 * 2);          // 5.2 MB
  u16* obufc= (u16*)alloc((size_t)1024 * 2560 * 2);          // 5.2 MB
  u16* shcat= (u16*)alloc((size_t)8192 * 384 * 2);           // 6.3 MB (z1 aliases)
  u16* tbuf = (u16*)alloc((size_t)8192 * 128 * 2);
  u16* dist = (u16*)alloc((size_t)8192 * 128 * 2);
  u16* hbuf = (u16*)alloc((size_t)8192 * 128 * 2);
  u16* gato = (u16*)alloc((size_t)8192 * 128 * 2);
  u16* sWT[3] = {(u16*)alloc(512*128*2), (u16*)alloc(1024*128*2), (u16*)alloc(1024*128*2)};
  u16* pWT[3] = {(u16*)alloc(512*128*2), (u16*)alloc(1024*128*2), (u16*)alloc(1024*128*2)};
  u16* r_f1wT = (u16*)alloc((size_t)128 * 2560 * 2);
  u16* WrPT   = (u16*)alloc((size_t)128 * 2560 * 2);
  u16* f_f1wT = (u16*)alloc(512 * 128 * 2);
  u16* WfPT   = (u16*)alloc(512 * 128 * 2);
  u16* f_qkv_wT = (u16*)alloc(384 * 128 * 2);
  u16* doWT   = (u16*)alloc(128 * 128 * 2);
  u16* gatWT  = (u16*)alloc(128 * 128 * 2);
  u16* i_f1wT = (u16*)alloc(512 * 128 * 2);
  u16* i_f2wT = (u16*)alloc(128 * 512 * 2);
  u16* f_f2wT = (u16*)alloc(128 * 512 * 2);
  u16* WmixT  = (u16*)alloc(128 * 384 * 2);
  u16* f_out_wB = (u16*)alloc(128 * 128 * 2);
  float* bmix = (float*)alloc(128 * 4);
  float* brP  = (float*)alloc(128 * 4);
  float* bfP  = (float*)alloc(512 * 4);
  float* invn = (float*)alloc(8192 * 4);
  float* as1b = (float*)alloc(8192 * 4);
  float* as2b = (float*)alloc(8192 * 4);
  float* routeF = (float*)alloc(8192 * 4);

  // A2 arena views (sequential lifetimes)
  u16* r_out_wB = (u16*)A2;                                  // prep
  u16* qkvc = (u16*)A2;                                      // router: [1024][7680]
  u16* fqkv = (u16*)A2;                                      // experts:
  u16* hidf = (u16*)(A2 + 6291456);
  u16* hidi = (u16*)(A2 + 6291456 + 8388608);
  u16* ofb  = (u16*)(A2 + 6291456 + 8388608 + 8388608);
  u16* outf = (u16*)(A2 + 6291456 + 8388608 + 8388608 + 2097152);
  u16* outi = (u16*)(A2 + 6291456 + 8388608 + 8388608 + 2097152 + 2097152);
  u16* z1   = shcat;                                         // shcat dead after distill1

  auto TR = [&](const float* in, u16* o, int R, int C) {
    transpose_f2b<<<dim3((C + 31) / 32, (R + 31) / 32), 256, 0, stream>>>(in, o, R, C);
  };

  // ---- prep: converts / transposes / folds ----
  f2b_copy<<<(2560*2560/4 + 255)/256, 256, 0, stream>>>(r_out_w, r_out_wB, 2560*2560/4);
  f2b_copy<<<(128*128/4 + 255)/256, 256, 0, stream>>>(f_out_w, f_out_wB, 128*128/4);
  TR(sW[0], sWT[0], 512, 128);  TR(sW[1], sWT[1], 1024, 128); TR(sW[2], sWT[2], 1024, 128);
  TR(pW[0], pWT[0], 512, 128);  TR(pW[1], pWT[1], 1024, 128); TR(pW[2], pWT[2], 1024, 128);
  TR(r_f1w, r_f1wT, 2560, 128);
  TR(f_f1w, f_f1wT, 128, 512);
  TR(f_qkv_w, f_qkv_wT, 128, 384);
  TR(doW, doWT, 128, 128); TR(gatW, gatWT, 128, 128);
  TR(i_f1w, i_f1wT, 128, 512); TR(i_f2w, i_f2wT, 512, 128); TR(f_f2w, f_f2wT, 512, 128);
  TR(r_qkv_w, r_qkv_wT, 2560, 7680);
  build_mix<<<192, 256, 0, stream>>>(dyn_w, dW[0], dW[1], dW[2], db[0], db[1], db[2], WmixT, bmix);
  bias_fold<<<1, 256, 0, stream>>>(r_out_b, r_f1w, r_f1b, brP, 2560, 128);
  bias_fold<<<2, 256, 0, stream>>>(f_out_b, f_f1w, f_f1b, bfP, 128, 512);
  // WrPT[128][2560] = r_f1wT @ r_out_w^T  (Bt operand is r_out_wB row-major!)
  gemm_mfma<<<dim3(20, 1), 256, 0, stream>>>(r_f1wT, 2560, r_out_wB, 2560, nullptr,
      WrPT, 2560, nullptr, 0, 2560, 0, -1, 0);
  // WfPT[512][128] = f_f1wT @ f_out_w^T
  gemm_mfma<<<dim3(1, 4), 256, 0, stream>>>(f_f1wT, 128, f_out_wB, 128, nullptr,
      WfPT, 128, nullptr, 0, 128, 0, -1, 0);

  // ---- feature decoupler ----
  const float* xs[3] = {x0, x1, x2};
  const int fd[3] = {512, 1024, 1024};
  const size_t off_sh[3] = {off_sh0, off_sh1, off_sh2};
  const size_t off_p[3] = {off_p0, off_p1, off_p2};
  for (int m = 0; m < 3; ++m) {
    f2b_copy<<<(8192*fd[m]/4 + 255)/256, 256, 0, stream>>>(xs[m], xb, 8192*fd[m]/4);
    gemm_mfma<<<dim3(1, 64), 256, 0, stream>>>(xb, fd[m], sWT[m], fd[m], sb[m],
        shcat + m * 128, 384, out + off_sh[m], 128, fd[m], 0, -1, 0);
    gemm_mfma<<<dim3(1, 64), 256, 0, stream>>>(xb, fd[m], pWT[m], fd[m], pb[m],
        nullptr, 0, out + off_p[m], 128, fd[m], 0, -1, 0);
  }

  // ---- distiller ----
  gemm_mfma<<<dim3(1, 64), 256, 0, stream>>>(shcat, 384, WmixT, 384, bmix,
      tbuf, 128, nullptr, 0, 384, 0, -1, 0);
  gemm_mfma<<<dim3(1, 64), 256, 0, stream>>>(tbuf, 128, doWT, 128, dob,
      dist, 128, out + off_dist, 128, 128, 0, -1, 0);

  // ---- GAT ----
  gemm_mfma<<<dim3(1, 64), 256, 0, stream>>>(dist, 128, gatWT, 128, nullptr,
      hbuf, 128, nullptr, 0, 128, 0, -1, 0);
  gat_prep<<<2048, 256, 0, stream>>>(dist, hbuf, att_src, att_dst, invn, as1b, as2b);
  gat_main<<<8192, 256, 0, stream>>>(dist, hbuf, invn, as1b, as2b, gat_b, gato);

  // ---- router: 8 n-chunks of 64 ----
  for (int c = 0; c < 8; ++c) {
    gather_f2b<<<(1024*640 + 255)/256, 256, 0, stream>>>(ctx, ctxb, c * 64);
    gemm_mfma<<<dim3(60, 8), 256, 0, stream>>>(ctxb, 2560, r_qkv_wT, 2560, r_qkv_b,
        qkvc, 7680, nullptr, 0, 2560, 0, -1, 0);
    router_attn<<<256, 256, 0, stream>>>(qkvc, obufc);
    gemm_mfma<<<dim3(1, 8), 256, 0, stream>>>(obufc, 2560, WrPT, 2560, brP,
        z1, 128, nullptr, 0, 2560, 1, /*oshift=*/6, /*on0=*/c * 64);
  }
  route_kernel<<<2048, 256, 0, stream>>>(z1, r_f2w, r_f2b, routeF, out + off_route);

  // ---- formal expert ----
  gemm_mfma<<<dim3(3, 64), 256, 0, stream>>>(gato, 128, f_qkv_wT, 128, f_qkv_b,
      fqkv, 384, nullptr, 0, 128, 0, -1, 0);
  formal_attn<<<512, 256, 0, stream>>>(fqkv, ofb);
  gemm_mfma<<<dim3(4, 64), 256, 0, stream>>>(ofb, 128, WfPT, 128, bfP,
      hidf, 512, nullptr, 0, 128, 1, -1, 0);
  gemm_mfma<<<dim3(1, 64), 256, 0, stream>>>(hidf, 512, f_f2wT, 512, f_f2b,
      outf, 128, nullptr, 0, 512, 0, -1, 0);

  // ---- informal expert ----
  gemm_mfma<<<dim3(4, 64), 256, 0, stream>>>(gato, 128, i_f1wT, 128, i_f1b,
      hidi, 512, nullptr, 0, 128, 1, -1, 0);
  gemm_mfma<<<dim3(1, 64), 256, 0, stream>>>(hidi, 512, i_f2wT, 512, i_f2b,
      outi, 128, nullptr, 0, 512, 0, -1, 0);

  // ---- mix ----
  combine_kernel<<<4096, 256, 0, stream>>>(routeF, outf, outi, out);
}